// Round 1
// baseline (439.552 us; speedup 1.0000x reference)
//
#include <hip/hip_runtime.h>

#define BIG_Z_F 1000000.0f
#define N_MESH 8

// One thread per pixel (h,w). Handles all N=8 meshes: cross-N dup/argmin
// reduction in registers, then writes all per-mesh outputs + the C=32
// interpolated feature channels per mesh.
__global__ __launch_bounds__(256) void raster_main(
    const float* __restrict__ zbuf,     // (N,HW)
    const int*   __restrict__ p2f,      // (N,HW)
    const float* __restrict__ bary,     // (N,HW,3)
    const float* __restrict__ dists,    // (N,HW)
    const float* __restrict__ fmem,     // (F,3,C)
    const int*   __restrict__ mdp,      // scalar mask_duplicate
    float* __restrict__ out_map,        // (N,C,HW)
    float* __restrict__ maskO,          // (N,HW)
    float* __restrict__ zbO,            // (N,HW)
    float* __restrict__ pO,             // (N,HW)  (int written as float)
    float* __restrict__ dO,             // (N,HW)
    float* __restrict__ bcO,            // (N,HW,3)
    int*   __restrict__ faceflag,       // (F) ws, pre-zeroed
    int HW, int C)
{
    const int pix = blockIdx.x * blockDim.x + threadIdx.x;
    if (pix >= HW) return;
    const int md = *mdp;   // uniform scalar load

    // Pass 1: cross-mesh reduction (covered count + argmin of masked z).
    float z[N_MESH];
    int count = 0;
    float best = __builtin_inff();
    int bidx = 0;
    #pragma unroll
    for (int n = 0; n < N_MESH; ++n) {
        const float zv = zbuf[n * HW + pix];
        z[n] = zv;
        count += (zv > -1.0f) ? 1 : 0;
        const float t = (zv < 0.0f) ? BIG_Z_F : zv;
        if (t < best) { best = t; bidx = n; }   // strict < => first-win tie, matches jnp.argmin
    }
    const bool dup0 = (count > 1);

    // Pass 2: per-mesh outputs.
    #pragma unroll
    for (int n = 0; n < N_MESH; ++n) {
        const int idx = n * HW + pix;
        const bool dup = dup0 && ((md != 0) || (n != bidx));
        const float zv = z[n];

        maskO[idx] = (zv >= 0.0f) ? 1.0f : 0.0f;
        zbO[idx]   = dup ? -1.0f : zv;

        const int p = dup ? -1 : p2f[idx];
        pO[idx] = (float)p;
        dO[idx] = dup ? -1.0f : dists[idx];

        float b0, b1, b2;
        if (dup) {
            b0 = -1.0f; b1 = -1.0f; b2 = -1.0f;
        } else {
            const float* bp = bary + (size_t)idx * 3;
            b0 = bp[0]; b1 = bp[1]; b2 = bp[2];
        }
        float* bo = bcO + (size_t)idx * 3;
        bo[0] = b0; bo[1] = b1; bo[2] = b2;

        const bool valid = (p >= 0);
        if (valid) faceflag[p] = 1;             // benign race: all store 1

        // Branchless interpolation: invalid lanes gather face 0 (uniform,
        // L1-hot) and multiply by 0 — exactly matches reference semantics.
        const int safe = valid ? p : 0;
        const float vmul = valid ? 1.0f : 0.0f;
        const float* a = fmem + (size_t)safe * 3 * C;
        #pragma unroll
        for (int c4 = 0; c4 < 32; c4 += 4) {    // C == 32
            const float4 a0 = *(const float4*)(a + c4);
            const float4 a1 = *(const float4*)(a + C + c4);
            const float4 a2 = *(const float4*)(a + 2 * C + c4);
            const float r0 = (b0 * a0.x + b1 * a1.x + b2 * a2.x) * vmul;
            const float r1 = (b0 * a0.y + b1 * a1.y + b2 * a2.y) * vmul;
            const float r2 = (b0 * a0.z + b1 * a1.z + b2 * a2.z) * vmul;
            const float r3 = (b0 * a0.w + b1 * a1.w + b2 * a2.w) * vmul;
            const int obase = (n * C + c4) * HW + pix;
            out_map[obase + 0 * HW] = r0;
            out_map[obase + 1 * HW] = r1;
            out_map[obase + 2 * HW] = r2;
            out_map[obase + 3 * HW] = r3;
        }
    }
}

// Scatter vertex visibility from face-visibility flags.
__global__ __launch_bounds__(256) void vert_vis(
    const int* __restrict__ faceflag,
    const int* __restrict__ pfaces,     // (F,3)
    float* __restrict__ vv,             // (V), pre-zeroed
    int F)
{
    const int f = blockIdx.x * blockDim.x + threadIdx.x;
    if (f >= F) return;
    if (faceflag[f]) {
        vv[pfaces[f * 3 + 0]] = 1.0f;
        vv[pfaces[f * 3 + 1]] = 1.0f;
        vv[pfaces[f * 3 + 2]] = 1.0f;
    }
}

extern "C" void kernel_launch(void* const* d_in, const int* in_sizes, int n_in,
                              void* d_out, int out_size, void* d_ws, size_t ws_size,
                              hipStream_t stream) {
    const float* zbuf   = (const float*)d_in[0];
    const int*   p2f    = (const int*)  d_in[1];
    const float* bary   = (const float*)d_in[2];
    const float* dists  = (const float*)d_in[3];
    const float* fmem   = (const float*)d_in[4];
    const int*   pfaces = (const int*)  d_in[5];
    // d_in[6] = num_verts (device scalar; V derived from out_size instead)
    const int*   mdp    = (const int*)  d_in[7];

    const long long P  = in_sizes[0];        // N*H*W*K = 2097152
    const int HW = (int)(P / N_MESH);        // 262144 pixels
    const int F3 = in_sizes[5];              // F*3
    const int F  = F3 / 3;                   // 20000
    const int C  = in_sizes[4] / F3;         // 32
    const int V  = (int)((long long)out_size - P * C - 7 * P);  // 10002

    float* out     = (float*)d_out;
    float* out_map = out;                    // P*C
    float* vv      = out_map + P * C;        // V
    float* maskO   = vv + V;                 // P
    float* zbO     = maskO + P;              // P
    float* pO      = zbO + P;                // P
    float* dO      = pO + P;                 // P
    float* bcO     = dO + P;                 // 3P

    int* faceflag = (int*)d_ws;              // F ints

    hipMemsetAsync(faceflag, 0, (size_t)F * sizeof(int), stream);
    hipMemsetAsync(vv, 0, (size_t)V * sizeof(float), stream);

    raster_main<<<dim3((HW + 255) / 256), dim3(256), 0, stream>>>(
        zbuf, p2f, bary, dists, fmem, mdp,
        out_map, maskO, zbO, pO, dO, bcO, faceflag, HW, C);

    vert_vis<<<dim3((F + 255) / 256), dim3(256), 0, stream>>>(
        faceflag, pfaces, vv, F);
}

// Round 2
// 424.123 us; speedup vs baseline: 1.0364x; 1.0364x over previous
//
#include <hip/hip_runtime.h>

#define BIG_Z_F 1000000.0f
#define N_MESH 8

// One thread per pixel (h,w). Handles all N=8 meshes: cross-N dup/argmin
// reduction in registers, then writes all per-mesh outputs + the C=32
// interpolated feature channels per mesh.
//
// Key insight: covered = z > -1 with p~0.84, so count>1 almost always and
// only the argmin mesh escapes the duplicate mask -> ~1 of 8 (n,pix) entries
// is valid. Predicating the 384B face_memory gather on valid cuts L2 gather
// traffic 8x (6.3 GB -> 0.8 GB), which was the R1 bottleneck.
__global__ __launch_bounds__(256) void raster_main(
    const float* __restrict__ zbuf,     // (N,HW)
    const int*   __restrict__ p2f,      // (N,HW)
    const float* __restrict__ bary,     // (N,HW,3)
    const float* __restrict__ dists,    // (N,HW)
    const float* __restrict__ fmem,     // (F,3,C)
    const int*   __restrict__ mdp,      // scalar mask_duplicate
    float* __restrict__ out_map,        // (N,C,HW)
    float* __restrict__ maskO,          // (N,HW)
    float* __restrict__ zbO,            // (N,HW)
    float* __restrict__ pO,             // (N,HW)  (int written as float)
    float* __restrict__ dO,             // (N,HW)
    float* __restrict__ bcO,            // (N,HW,3)
    int*   __restrict__ faceflag,       // (F) ws, pre-zeroed
    int HW, int C)
{
    const int pix = blockIdx.x * blockDim.x + threadIdx.x;
    if (pix >= HW) return;
    const int md = *mdp;   // uniform scalar load

    // Pass 1: cross-mesh reduction (covered count + argmin of masked z).
    float z[N_MESH];
    int count = 0;
    float best = __builtin_inff();
    int bidx = 0;
    #pragma unroll
    for (int n = 0; n < N_MESH; ++n) {
        const float zv = __builtin_nontemporal_load(&zbuf[n * HW + pix]);
        z[n] = zv;
        count += (zv > -1.0f) ? 1 : 0;
        const float t = (zv < 0.0f) ? BIG_Z_F : zv;
        if (t < best) { best = t; bidx = n; }   // strict < => first-win tie, matches jnp.argmin
    }
    const bool dup0 = (count > 1);

    // Pass 2: per-mesh outputs.
    #pragma unroll
    for (int n = 0; n < N_MESH; ++n) {
        const int idx = n * HW + pix;
        const bool dup = dup0 && ((md != 0) || (n != bidx));
        const float zv = z[n];

        __builtin_nontemporal_store((zv >= 0.0f) ? 1.0f : 0.0f, &maskO[idx]);
        __builtin_nontemporal_store(dup ? -1.0f : zv, &zbO[idx]);

        const int p = dup ? -1 : __builtin_nontemporal_load(&p2f[idx]);
        __builtin_nontemporal_store((float)p, &pO[idx]);
        __builtin_nontemporal_store(
            dup ? -1.0f : __builtin_nontemporal_load(&dists[idx]), &dO[idx]);

        float b0, b1, b2;
        {
            const float* bp = bary + (size_t)idx * 3;
            b0 = dup ? -1.0f : __builtin_nontemporal_load(bp + 0);
            b1 = dup ? -1.0f : __builtin_nontemporal_load(bp + 1);
            b2 = dup ? -1.0f : __builtin_nontemporal_load(bp + 2);
        }
        float* bo = bcO + (size_t)idx * 3;
        __builtin_nontemporal_store(b0, bo + 0);
        __builtin_nontemporal_store(b1, bo + 1);
        __builtin_nontemporal_store(b2, bo + 2);

        const bool valid = (p >= 0);
        if (valid) faceflag[p] = 1;             // benign race: all store 1

        // Gather + interpolate ONLY for valid lanes (exec-masked loads fetch
        // nothing for invalid lanes). Accumulators default to 0 so the store
        // stays unconditional and full-wave coalesced.
        const float* a = fmem + (size_t)(valid ? p : 0) * 3 * C;
        #pragma unroll
        for (int c4 = 0; c4 < 32; c4 += 4) {    // C == 32
            float r0 = 0.0f, r1 = 0.0f, r2 = 0.0f, r3 = 0.0f;
            if (valid) {
                const float4 a0 = *(const float4*)(a + c4);
                const float4 a1 = *(const float4*)(a + C + c4);
                const float4 a2 = *(const float4*)(a + 2 * C + c4);
                r0 = b0 * a0.x + b1 * a1.x + b2 * a2.x;
                r1 = b0 * a0.y + b1 * a1.y + b2 * a2.y;
                r2 = b0 * a0.z + b1 * a1.z + b2 * a2.z;
                r3 = b0 * a0.w + b1 * a1.w + b2 * a2.w;
            }
            const int obase = (n * C + c4) * HW + pix;
            __builtin_nontemporal_store(r0, &out_map[obase + 0 * HW]);
            __builtin_nontemporal_store(r1, &out_map[obase + 1 * HW]);
            __builtin_nontemporal_store(r2, &out_map[obase + 2 * HW]);
            __builtin_nontemporal_store(r3, &out_map[obase + 3 * HW]);
        }
    }
}

// Scatter vertex visibility from face-visibility flags.
__global__ __launch_bounds__(256) void vert_vis(
    const int* __restrict__ faceflag,
    const int* __restrict__ pfaces,     // (F,3)
    float* __restrict__ vv,             // (V), pre-zeroed
    int F)
{
    const int f = blockIdx.x * blockDim.x + threadIdx.x;
    if (f >= F) return;
    if (faceflag[f]) {
        vv[pfaces[f * 3 + 0]] = 1.0f;
        vv[pfaces[f * 3 + 1]] = 1.0f;
        vv[pfaces[f * 3 + 2]] = 1.0f;
    }
}

extern "C" void kernel_launch(void* const* d_in, const int* in_sizes, int n_in,
                              void* d_out, int out_size, void* d_ws, size_t ws_size,
                              hipStream_t stream) {
    const float* zbuf   = (const float*)d_in[0];
    const int*   p2f    = (const int*)  d_in[1];
    const float* bary   = (const float*)d_in[2];
    const float* dists  = (const float*)d_in[3];
    const float* fmem   = (const float*)d_in[4];
    const int*   pfaces = (const int*)  d_in[5];
    // d_in[6] = num_verts (device scalar; V derived from out_size instead)
    const int*   mdp    = (const int*)  d_in[7];

    const long long P  = in_sizes[0];        // N*H*W*K = 2097152
    const int HW = (int)(P / N_MESH);        // 262144 pixels
    const int F3 = in_sizes[5];              // F*3
    const int F  = F3 / 3;                   // 20000
    const int C  = in_sizes[4] / F3;         // 32
    const int V  = (int)((long long)out_size - P * C - 7 * P);  // 10002

    float* out     = (float*)d_out;
    float* out_map = out;                    // P*C
    float* vv      = out_map + P * C;        // V
    float* maskO   = vv + V;                 // P
    float* zbO     = maskO + P;              // P
    float* pO      = zbO + P;                // P
    float* dO      = pO + P;                 // P
    float* bcO     = dO + P;                 // 3P

    int* faceflag = (int*)d_ws;              // F ints

    hipMemsetAsync(faceflag, 0, (size_t)F * sizeof(int), stream);
    hipMemsetAsync(vv, 0, (size_t)V * sizeof(float), stream);

    raster_main<<<dim3((HW + 255) / 256), dim3(256), 0, stream>>>(
        zbuf, p2f, bary, dists, fmem, mdp,
        out_map, maskO, zbO, pO, dO, bcO, faceflag, HW, C);

    vert_vis<<<dim3((F + 255) / 256), dim3(256), 0, stream>>>(
        faceflag, pfaces, vv, F);
}